// Round 3
// baseline (32270.001 us; speedup 1.0000x reference)
//
#include <hip/hip_runtime.h>

// ---------------------------------------------------------------------------
// Persistent weight-stationary LSTM, bf16 MFMA, 64 blocks, relaxed flat barrier.
//  - Blocks 0..31: layer0 (tick t=i). Blocks 32..63: layer1 (tick t=i-1).
//  - Each block owns 16 h-columns; wave w computes gate w (16x16 n-tile, m=64).
//  - Weights bf16, packed once to B-frag order, VGPR-resident for all ticks.
//  - Per tick per block: ONE release fence (wbl2) + relaxed counter store,
//    flat poll of 64 counters (lane i <-> counter i), ONE acquire fence (inv).
//  - h state bf16 ping-pong in ws; c state register-resident.
// ---------------------------------------------------------------------------

#define TT 1024
#define BB 64
#define CC 256
#define HH 512
#define Y_ELEMS (TT * BB * HH)
#define S_ELEMS (BB * HH)

typedef __attribute__((ext_vector_type(8))) short bf16x8;
typedef __attribute__((ext_vector_type(4))) float f32x4;
typedef unsigned int u32;
typedef unsigned short u16;

// ---- ws layout (bytes) ----
#define WS_CNT 0           // 64 counters, 128B-spaced (8 KB)
#define WS_BSUM0 8192      // 2048 f32
#define WS_BSUM1 16384     // 2048 f32
#define WS_H0 24576        // 2 * 32768 u16 (h0 ping-pong)
#define WS_H1 155648       // 2 * 32768 u16 (h1 ping-pong)
#define WS_WPK0 286720     // 2048*768 bf16 packed  (3 MB)
#define WS_WPK1 3432448    // 2048*1024 bf16 packed (4 MB)
// end 7,626,752 B

__device__ __forceinline__ u16 f2b_rne(float f) {
    u32 u = __float_as_uint(f);
    return (u16)((u + 0x7FFFu + ((u >> 16) & 1u)) >> 16);
}
__device__ __forceinline__ u16 f2b_fast(float f) {
    return (u16)((__float_as_uint(f) + 0x8000u) >> 16);
}
__device__ __forceinline__ float sigf(float z) { return 1.0f / (1.0f + __expf(-z)); }
__device__ __forceinline__ float tanh_f(float z) { return 2.0f / (1.0f + __expf(-2.0f * z)) - 1.0f; }

__device__ __forceinline__ bf16x8 pack8(float4 a, float4 b) {
    union { u16 u[8]; bf16x8 v; } r;
    r.u[0] = f2b_fast(a.x); r.u[1] = f2b_fast(a.y); r.u[2] = f2b_fast(a.z); r.u[3] = f2b_fast(a.w);
    r.u[4] = f2b_fast(b.x); r.u[5] = f2b_fast(b.y); r.u[6] = f2b_fast(b.z); r.u[7] = f2b_fast(b.w);
    return r.v;
}

// ---- init: zero counters, bsum = bih+bhh, h buffers <- bf16(initial h) ----
__global__ void k_init(const float* __restrict__ bih0, const float* __restrict__ bhh0,
                       const float* __restrict__ bih1, const float* __restrict__ bhh1,
                       const float* __restrict__ h00, const float* __restrict__ h01,
                       unsigned char* __restrict__ ws) {
    u32* cnt = (u32*)(ws + WS_CNT);
    float* bs0 = (float*)(ws + WS_BSUM0);
    float* bs1 = (float*)(ws + WS_BSUM1);
    u16* h0 = (u16*)(ws + WS_H0);
    u16* h1 = (u16*)(ws + WS_H1);
    int t = blockIdx.x * 256 + threadIdx.x;  // 32768 threads
    if (t < 2048) cnt[t] = 0u;
    if (t < 2048) { bs0[t] = bih0[t] + bhh0[t]; bs1[t] = bih1[t] + bhh1[t]; }
    if (t < S_ELEMS) { h0[t] = f2b_rne(h00[t]); h1[t] = f2b_rne(h01[t]); }
}

// ---- weight pack: fp32 [4H,K] -> bf16 B-frag order ----
// frag index u = ((blk*4 + wv)*NKT + kt)*64 + lane; each thread writes 8 elems.
// B row for n-index (lane&15): row = wv*512 + blk*16 + (lane&15); k = kt*32+(lane>>4)*8
__global__ void k_wprep(const float* __restrict__ Wih0, const float* __restrict__ Whh0,
                        const float* __restrict__ Wih1, const float* __restrict__ Whh1,
                        unsigned char* __restrict__ ws) {
    u16* wpk0 = (u16*)(ws + WS_WPK0);
    u16* wpk1 = (u16*)(ws + WS_WPK1);
    int u = blockIdx.x * 256 + threadIdx.x;  // 458752 threads total
    const float* s;
    u16* d;
    if (u < 32 * 4 * 24 * 64) {  // layer0: NKT=24 (8 x-tiles K=256, 16 h-tiles K=512)
        int lane = u & 63;
        int kt = (u >> 6) % 24;
        int wv = (u / (24 * 64)) & 3;
        int blk = u / (4 * 24 * 64);
        int row = wv * 512 + blk * 16 + (lane & 15);
        int kk = kt * 32 + (lane >> 4) * 8;
        s = (kk < 256) ? (Wih0 + (size_t)row * 256 + kk) : (Whh0 + (size_t)row * 512 + (kk - 256));
        d = wpk0 + (size_t)u * 8;
    } else {                     // layer1: NKT=32 (16 y0-tiles, 16 h1-tiles, K=1024)
        int v = u - 32 * 4 * 24 * 64;
        int lane = v & 63;
        int kt = (v >> 6) % 32;
        int wv = (v / (32 * 64)) & 3;
        int blk = v / (4 * 32 * 64);
        int row = wv * 512 + blk * 16 + (lane & 15);
        int kk = kt * 32 + (lane >> 4) * 8;
        s = (kk < 512) ? (Wih1 + (size_t)row * 512 + kk) : (Whh1 + (size_t)row * 512 + (kk - 512));
        d = wpk1 + (size_t)v * 8;
    }
    #pragma unroll
    for (int i = 0; i < 8; ++i) d[i] = f2b_rne(s[i]);
}

// ---- persistent tick loop ----
template <int LAYER>
__device__ void run_ticks(const float* __restrict__ x, const float* __restrict__ c0,
                          float* __restrict__ out, unsigned char* __restrict__ ws,
                          int bidL, int bid, float* __restrict__ gb /*[4][64][17]*/) {
    constexpr int NKT = (LAYER == 0) ? 24 : 32;
    u32* cnt = (u32*)(ws + WS_CNT);
    const float* bs = (const float*)(ws + (LAYER == 0 ? WS_BSUM0 : WS_BSUM1));
    u16* h0b[2] = { (u16*)(ws + WS_H0), (u16*)(ws + WS_H0) + S_ELEMS };
    u16* h1b[2] = { (u16*)(ws + WS_H1), (u16*)(ws + WS_H1) + S_ELEMS };
    const u16* wpk = (const u16*)(ws + (LAYER == 0 ? WS_WPK0 : WS_WPK1));

    const int tid = threadIdx.x, lane = tid & 63, wv = tid >> 6;
    const int r16 = lane & 15, quad = lane >> 4, q8 = quad * 8;
    const int jb = bidL * 16;

    // B-frags: VGPR-resident for all ticks
    bf16x8 wfr[NKT];
    {
        const u16* wp = wpk + (size_t)((bidL * 4 + wv) * NKT) * 512 + (size_t)lane * 8;
        #pragma unroll
        for (int kt = 0; kt < NKT; ++kt) wfr[kt] = *(const bf16x8*)(wp + (size_t)kt * 512);
    }

    // epilogue ownership: thread -> (jl, 4 batches)
    const int jl = tid & 15;
    const int bq = tid >> 4;      // 0..15
    const int col = jb + jl;
    float bias[4], cst[4];
    #pragma unroll
    for (int g = 0; g < 4; ++g) bias[g] = bs[g * HH + col];
    #pragma unroll
    for (int r = 0; r < 4; ++r) cst[r] = c0[(bq * 4 + r) * HH + col];

    for (int i = 0; i <= TT; ++i) {
        const bool active = (LAYER == 0) ? (i < TT) : (i >= 1);
        const int t = (LAYER == 0) ? i : i - 1;
        if (active) {
            f32x4 aE[4], aO[4];
            #pragma unroll
            for (int mt = 0; mt < 4; ++mt) {
                aE[mt][0]=0.f; aE[mt][1]=0.f; aE[mt][2]=0.f; aE[mt][3]=0.f;
                aO[mt][0]=0.f; aO[mt][1]=0.f; aO[mt][2]=0.f; aO[mt][3]=0.f;
            }
            if (LAYER == 0) {
                const float* xb = x + (size_t)t * BB * CC;
                #pragma unroll
                for (int kt = 0; kt < 8; ++kt) {
                    #pragma unroll
                    for (int mt = 0; mt < 4; ++mt) {
                        const float* p = xb + (size_t)(mt * 16 + r16) * CC + kt * 32 + q8;
                        float4 f0 = *(const float4*)p;
                        float4 f1 = *(const float4*)(p + 4);
                        bf16x8 a = pack8(f0, f1);
                        if (kt & 1) aO[mt] = __builtin_amdgcn_mfma_f32_16x16x32_bf16(a, wfr[kt], aO[mt], 0, 0, 0);
                        else        aE[mt] = __builtin_amdgcn_mfma_f32_16x16x32_bf16(a, wfr[kt], aE[mt], 0, 0, 0);
                    }
                }
                const u16* hp = h0b[i & 1];
                #pragma unroll
                for (int kt = 0; kt < 16; ++kt) {
                    #pragma unroll
                    for (int mt = 0; mt < 4; ++mt) {
                        bf16x8 a = *(const bf16x8*)(hp + (size_t)(mt * 16 + r16) * HH + kt * 32 + q8);
                        if (kt & 1) aO[mt] = __builtin_amdgcn_mfma_f32_16x16x32_bf16(a, wfr[8 + kt], aO[mt], 0, 0, 0);
                        else        aE[mt] = __builtin_amdgcn_mfma_f32_16x16x32_bf16(a, wfr[8 + kt], aE[mt], 0, 0, 0);
                    }
                }
            } else {
                const u16* pa = h0b[(t + 1) & 1];   // y0[t]
                const u16* pb = h1b[t & 1];         // h1[t-1]
                #pragma unroll
                for (int kt = 0; kt < 16; ++kt) {
                    #pragma unroll
                    for (int mt = 0; mt < 4; ++mt) {
                        bf16x8 a = *(const bf16x8*)(pa + (size_t)(mt * 16 + r16) * HH + kt * 32 + q8);
                        if (kt & 1) aO[mt] = __builtin_amdgcn_mfma_f32_16x16x32_bf16(a, wfr[kt], aO[mt], 0, 0, 0);
                        else        aE[mt] = __builtin_amdgcn_mfma_f32_16x16x32_bf16(a, wfr[kt], aE[mt], 0, 0, 0);
                    }
                }
                #pragma unroll
                for (int kt = 0; kt < 16; ++kt) {
                    #pragma unroll
                    for (int mt = 0; mt < 4; ++mt) {
                        bf16x8 a = *(const bf16x8*)(pb + (size_t)(mt * 16 + r16) * HH + kt * 32 + q8);
                        if (kt & 1) aO[mt] = __builtin_amdgcn_mfma_f32_16x16x32_bf16(a, wfr[16 + kt], aO[mt], 0, 0, 0);
                        else        aE[mt] = __builtin_amdgcn_mfma_f32_16x16x32_bf16(a, wfr[16 + kt], aE[mt], 0, 0, 0);
                    }
                }
            }
            // gates -> LDS (wave = gate), padded stride 17 (conflict-free)
            #pragma unroll
            for (int mt = 0; mt < 4; ++mt) {
                f32x4 acc = aE[mt] + aO[mt];
                #pragma unroll
                for (int r = 0; r < 4; ++r)
                    gb[(wv * 64 + mt * 16 + quad * 4 + r) * 17 + r16] = acc[r];
            }
            __syncthreads();
            u16* hw = (LAYER == 0) ? h0b[(t + 1) & 1] : h1b[(t + 1) & 1];
            #pragma unroll
            for (int r = 0; r < 4; ++r) {
                int b = bq * 4 + r;
                float zi = gb[(0 * 64 + b) * 17 + jl] + bias[0];
                float zf = gb[(1 * 64 + b) * 17 + jl] + bias[1];
                float zg = gb[(2 * 64 + b) * 17 + jl] + bias[2];
                float zo = gb[(3 * 64 + b) * 17 + jl] + bias[3];
                float gi = sigf(zi), gf = sigf(zf), gg = tanh_f(zg), go = sigf(zo);
                float cn = gf * cst[r] + gi * gg;
                cst[r] = cn;
                float h = go * tanh_f(cn);
                hw[b * HH + col] = f2b_rne(h);
                if (LAYER == 1) out[(size_t)t * S_ELEMS + b * HH + col] = h;
                if (t == TT - 1) {
                    float* fin = out + Y_ELEMS + (LAYER == 0 ? 0 : 2) * S_ELEMS;
                    fin[b * HH + col] = h;
                    fin[S_ELEMS + b * HH + col] = cn;
                }
            }
        }
        // ---- barrier: drain stores, release once, arrive, poll, acquire once ----
        __syncthreads();
        if (tid == 0) {
            __builtin_amdgcn_fence(__ATOMIC_RELEASE, "agent");   // wbl2 only
            __hip_atomic_store(&cnt[bid * 32], (u32)(i + 1), __ATOMIC_RELAXED, __HIP_MEMORY_SCOPE_AGENT);
        }
        if (wv == 0) {
            const u32 target = (u32)(i + 1);
            for (;;) {
                u32 v = __hip_atomic_load(&cnt[lane * 32], __ATOMIC_RELAXED, __HIP_MEMORY_SCOPE_AGENT);
                if (__ballot(v >= target) == ~0ull) break;
                __builtin_amdgcn_s_sleep(1);
            }
        }
        __syncthreads();
        __builtin_amdgcn_fence(__ATOMIC_ACQUIRE, "agent");       // buffer_inv only
    }
}

__global__ __launch_bounds__(256, 1) void k_lstm(const float* __restrict__ x,
                                                 const float* __restrict__ c00,
                                                 const float* __restrict__ c01,
                                                 float* __restrict__ out,
                                                 unsigned char* __restrict__ ws) {
    __shared__ float gb[4 * 64 * 17];   // 17.4 KB gate-exchange buffer
    const int bid = blockIdx.x;
    if (bid < 32) run_ticks<0>(x, c00, out, ws, bid, bid, gb);
    else          run_ticks<1>(x, c01, out, ws, bid - 32, bid, gb);
}

extern "C" void kernel_launch(void* const* d_in, const int* in_sizes, int n_in,
                              void* d_out, int out_size, void* d_ws, size_t ws_size,
                              hipStream_t stream) {
    const float* x    = (const float*)d_in[0];
    const float* h0_0 = (const float*)d_in[1];
    const float* c0_0 = (const float*)d_in[2];
    const float* h0_1 = (const float*)d_in[3];
    const float* c0_1 = (const float*)d_in[4];
    const float* Wih0 = (const float*)d_in[5];
    const float* Whh0 = (const float*)d_in[6];
    const float* bih0 = (const float*)d_in[7];
    const float* bhh0 = (const float*)d_in[8];
    const float* Wih1 = (const float*)d_in[9];
    const float* Whh1 = (const float*)d_in[10];
    const float* bih1 = (const float*)d_in[11];
    const float* bhh1 = (const float*)d_in[12];
    float* out = (float*)d_out;
    unsigned char* ws = (unsigned char*)d_ws;

    k_init<<<128, 256, 0, stream>>>(bih0, bhh0, bih1, bhh1, h0_0, h0_1, ws);
    k_wprep<<<1792, 256, 0, stream>>>(Wih0, Whh0, Wih1, Whh1, ws);
    k_lstm<<<64, 256, 0, stream>>>(x, c0_0, c0_1, out, ws);
}